// Round 1
// baseline (479.535 us; speedup 1.0000x reference)
//
#include <hip/hip_runtime.h>
#include <hip/hip_bf16.h>

#define NN 20000
#define NE 640000
#define IN_F 512
#define H1_F 256
#define H2_F 128

// ---------------- degree / weighted-degree accumulation ----------------
__global__ void deg_kernel(const float* __restrict__ ew, const int* __restrict__ src,
                           const int* __restrict__ dst,
                           float* __restrict__ out_wsum, float* __restrict__ in_wsum,
                           int* __restrict__ out_cnt, int* __restrict__ in_cnt, int E) {
    int stride = gridDim.x * blockDim.x;
    for (int e = blockIdx.x * blockDim.x + threadIdx.x; e < E; e += stride) {
        float w = ew[e];
        int s = src[e], d = dst[e];
        atomicAdd(&out_wsum[s], w);
        atomicAdd(&in_wsum[d], w);
        atomicAdd(&out_cnt[s], 1);
        atomicAdd(&in_cnt[d], 1);
    }
}

// ---------------- exclusive scan of in-degree counts (single block) ----------------
__global__ void scan_kernel(const int* __restrict__ cnt, int* __restrict__ row_start,
                            int* __restrict__ cursor, int n) {
    __shared__ int ls[1024];
    int tid = threadIdx.x;
    int chunk = (n + 1023) >> 10;
    int begin = tid * chunk;
    int end = begin + chunk; if (end > n) end = n;
    int s = 0;
    for (int i = begin; i < end; ++i) s += cnt[i];
    ls[tid] = s;
    __syncthreads();
    // Hillis-Steele inclusive scan over 1024 partials
    for (int d = 1; d < 1024; d <<= 1) {
        int v = (tid >= d) ? ls[tid - d] : 0;
        __syncthreads();
        ls[tid] += v;
        __syncthreads();
    }
    int run = ls[tid] - s;  // exclusive base for this chunk
    for (int i = begin; i < end; ++i) {
        row_start[i] = run;
        cursor[i] = run;
        run += cnt[i];
    }
}

// ---------------- bucket edge ids by dst ----------------
__global__ void scatter_kernel(const int* __restrict__ dst, int* __restrict__ cursor,
                               int* __restrict__ sorted_eid, int E) {
    int stride = gridDim.x * blockDim.x;
    for (int e = blockIdx.x * blockDim.x + threadIdx.x; e < E; e += stride) {
        int p = atomicAdd(&cursor[dst[e]], 1);
        sorted_eid[p] = e;
    }
}

// ---------------- fp32 tiled GEMM: C[M,Nn] = A[M,K] @ B[K,Nn] ----------------
// BM=64, BN=64, BK=16, 256 threads, 4x4 per thread.
// ROWSCALE: multiply each output row by rsqrt(max(rowcnt[r],1)).
template <bool ROWSCALE>
__global__ void gemm_f32(const float* __restrict__ A, const float* __restrict__ B,
                         float* __restrict__ C, const int* __restrict__ rowcnt,
                         int M, int Nn, int K) {
    __shared__ float As[16][65];
    __shared__ float Bs[16][64];
    const int tid = threadIdx.x;
    const int tx = tid & 15, ty = tid >> 4;
    const int brow = blockIdx.x * 64, bcol = blockIdx.y * 64;
    float acc[4][4] = {};
    for (int k0 = 0; k0 < K; k0 += 16) {
        {   // A tile: 64x16 floats = 256 float4
            int row = tid >> 2, k4 = (tid & 3) * 4;
            int gr = brow + row;
            float4 a = (gr < M) ? *(const float4*)&A[(size_t)gr * K + k0 + k4]
                                : make_float4(0.f, 0.f, 0.f, 0.f);
            As[k4 + 0][row] = a.x; As[k4 + 1][row] = a.y;
            As[k4 + 2][row] = a.z; As[k4 + 3][row] = a.w;
        }
        {   // B tile: 16x64 floats = 256 float4
            int kr = tid >> 4, c4 = (tid & 15) * 4;
            *(float4*)&Bs[kr][c4] = *(const float4*)&B[(size_t)(k0 + kr) * Nn + bcol + c4];
        }
        __syncthreads();
#pragma unroll
        for (int k = 0; k < 16; ++k) {
            float a[4], b[4];
#pragma unroll
            for (int i = 0; i < 4; ++i) a[i] = As[k][ty * 4 + i];
#pragma unroll
            for (int j = 0; j < 4; ++j) b[j] = Bs[k][tx * 4 + j];
#pragma unroll
            for (int i = 0; i < 4; ++i)
#pragma unroll
                for (int j = 0; j < 4; ++j) acc[i][j] = fmaf(a[i], b[j], acc[i][j]);
        }
        __syncthreads();
    }
#pragma unroll
    for (int i = 0; i < 4; ++i) {
        int r = brow + ty * 4 + i;
        if (r >= M) continue;
        float scale = 1.f;
        if (ROWSCALE) scale = rsqrtf(fmaxf((float)rowcnt[r], 1.f));
        float4 v = make_float4(acc[i][0] * scale, acc[i][1] * scale,
                               acc[i][2] * scale, acc[i][3] * scale);
        *(float4*)&C[(size_t)r * Nn + bcol + tx * 4] = v;
    }
}

// ---------------- SpMM1: h1[d] = relu(sum_e nw_e * h[src_e] + b1), 1 wave/node ----------------
__global__ void spmm1_kernel(const float* __restrict__ h, const float* __restrict__ ew,
                             const int* __restrict__ src,
                             const float* __restrict__ out_wsum, const float* __restrict__ in_wsum,
                             const int* __restrict__ row_start, const int* __restrict__ in_cnt,
                             const int* __restrict__ sorted_eid, const float* __restrict__ b1,
                             float* __restrict__ h1out) {
    int node = blockIdx.x;
    int lane = threadIdx.x;  // 64 lanes * float4 = 256 feats
    int start = row_start[node], cnt = in_cnt[node];
    float rin = (cnt > 0) ? rsqrtf(in_wsum[node]) : 0.f;
    float4 acc = make_float4(0.f, 0.f, 0.f, 0.f);
    for (int j = 0; j < cnt; ++j) {
        int e = sorted_eid[start + j];
        int s = src[e];
        float w = ew[e] * rsqrtf(out_wsum[s]) * rin;
        float4 v = *(const float4*)&h[(size_t)s * H1_F + lane * 4];
        acc.x = fmaf(w, v.x, acc.x); acc.y = fmaf(w, v.y, acc.y);
        acc.z = fmaf(w, v.z, acc.z); acc.w = fmaf(w, v.w, acc.w);
    }
    float4 bb = *(const float4*)&b1[lane * 4];
    acc.x = fmaxf(acc.x + bb.x, 0.f); acc.y = fmaxf(acc.y + bb.y, 0.f);
    acc.z = fmaxf(acc.z + bb.z, 0.f); acc.w = fmaxf(acc.w + bb.w, 0.f);
    *(float4*)&h1out[(size_t)node * H1_F + lane * 4] = acc;
}

// ---------------- SpMM2: out[d] = rsqrt(max(indeg,1)) * sum_e h2[src_e] + b2 ----------------
__global__ void spmm2_kernel(const float* __restrict__ h2, const int* __restrict__ src,
                             const int* __restrict__ row_start, const int* __restrict__ in_cnt,
                             const int* __restrict__ sorted_eid, const float* __restrict__ b2,
                             float* __restrict__ out) {
    int node = blockIdx.x;
    int lane = threadIdx.x;  // 64 lanes * float2 = 128 feats
    int start = row_start[node], cnt = in_cnt[node];
    float2 acc = make_float2(0.f, 0.f);
    for (int j = 0; j < cnt; ++j) {
        int e = sorted_eid[start + j];
        int s = src[e];
        float2 v = *(const float2*)&h2[(size_t)s * H2_F + lane * 2];
        acc.x += v.x; acc.y += v.y;
    }
    float rin = rsqrtf(fmaxf((float)cnt, 1.f));
    float2 bb = *(const float2*)&b2[lane * 2];
    float2 r = make_float2(acc.x * rin + bb.x, acc.y * rin + bb.y);
    *(float2*)&out[(size_t)node * H2_F + lane * 2] = r;
}

extern "C" void kernel_launch(void* const* d_in, const int* in_sizes, int n_in,
                              void* d_out, int out_size, void* d_ws, size_t ws_size,
                              hipStream_t stream) {
    const float* features = (const float*)d_in[0];
    const float* edge_w   = (const float*)d_in[1];
    const int*   src      = (const int*)d_in[2];
    const int*   dst      = (const int*)d_in[3];
    const float* W1       = (const float*)d_in[4];
    const float* b1       = (const float*)d_in[5];
    const float* W2       = (const float*)d_in[6];
    const float* b2       = (const float*)d_in[7];
    float* out = (float*)d_out;

    const int N = in_sizes[0] / IN_F;   // 20000
    const int E = in_sizes[1];          // 640000

    // ---- workspace carve-up (256B aligned) ----
    char* base = (char*)d_ws;
    size_t off = 0;
    auto alloc = [&](size_t bytes) {
        char* p = base + off;
        off = (off + bytes + 255) & ~(size_t)255;
        return p;
    };
    float* out_wsum   = (float*)alloc((size_t)N * 4);
    float* in_wsum    = (float*)alloc((size_t)N * 4);
    int*   out_cnt    = (int*)  alloc((size_t)N * 4);
    int*   in_cnt     = (int*)  alloc((size_t)N * 4);
    int*   row_start  = (int*)  alloc((size_t)N * 4);
    int*   cursor     = (int*)  alloc((size_t)N * 4);
    int*   sorted_eid = (int*)  alloc((size_t)E * 4);
    float* h_tmp1     = (float*)alloc((size_t)N * H1_F * 4);
    float* h1         = (float*)alloc((size_t)N * H1_F * 4);
    float* h_tmp2     = (float*)alloc((size_t)N * H2_F * 4);
    (void)ws_size;

    // ---- zero accumulators ----
    hipMemsetAsync(out_wsum, 0, (size_t)N * 4, stream);
    hipMemsetAsync(in_wsum,  0, (size_t)N * 4, stream);
    hipMemsetAsync(out_cnt,  0, (size_t)N * 4, stream);
    hipMemsetAsync(in_cnt,   0, (size_t)N * 4, stream);

    // ---- degrees + weighted degrees ----
    deg_kernel<<<1024, 256, 0, stream>>>(edge_w, src, dst, out_wsum, in_wsum,
                                         out_cnt, in_cnt, E);
    // ---- CSR by dst ----
    scan_kernel<<<1, 1024, 0, stream>>>(in_cnt, row_start, cursor, N);
    scatter_kernel<<<1024, 256, 0, stream>>>(dst, cursor, sorted_eid, E);

    // ---- layer 1: h_tmp1 = features @ W1 ----
    dim3 g1((N + 63) / 64, H1_F / 64);
    gemm_f32<false><<<g1, 256, 0, stream>>>(features, W1, h_tmp1, nullptr, N, H1_F, IN_F);
    // ---- SpMM1 + bias + relu ----
    spmm1_kernel<<<N, 64, 0, stream>>>(h_tmp1, edge_w, src, out_wsum, in_wsum,
                                       row_start, in_cnt, sorted_eid, b1, h1);
    // ---- layer 2: h_tmp2 = (h1 @ W2) * rsqrt(max(outdeg,1)) per row ----
    dim3 g2((N + 63) / 64, H2_F / 64);
    gemm_f32<true><<<g2, 256, 0, stream>>>(h1, W2, h_tmp2, out_cnt, N, H2_F, H1_F);
    // ---- SpMM2 + in-norm + bias ----
    spmm2_kernel<<<N, 64, 0, stream>>>(h_tmp2, src, row_start, in_cnt, sorted_eid, b2, out);
}

// Round 2
// 372.741 us; speedup vs baseline: 1.2865x; 1.2865x over previous
//
#include <hip/hip_runtime.h>
#include <hip/hip_bf16.h>
#include <stdint.h>

#define NN 20000
#define IN_F 512
#define H1_F 256
#define H2_F 128
#define MPAD 20096   // 157*128, padded row count for 128-row GEMM tiles

typedef __attribute__((ext_vector_type(8))) short short8;   // 8 bf16 (4 VGPRs)
typedef __attribute__((ext_vector_type(4))) float f32x4;
typedef __attribute__((ext_vector_type(4))) uint32_t u32x4;

// ---- fp32 -> (bf16 main | bf16 residual) packed in one u32 ----
__device__ inline uint32_t pack_hl(float x) {
    __hip_bfloat16 m = __float2bfloat16(x);
    float mf = __bfloat162float(m);
    __hip_bfloat16 r = __float2bfloat16(x - mf);
    return (uint32_t)__builtin_bit_cast(unsigned short, m) |
           ((uint32_t)__builtin_bit_cast(unsigned short, r) << 16);
}

__device__ inline void gld_lds16(const uint32_t* g, uint32_t* l) {
    __builtin_amdgcn_global_load_lds((const __attribute__((address_space(1))) uint32_t*)g,
                                     (__attribute__((address_space(3))) uint32_t*)l,
                                     16, 0, 0);
}

// ---------------- degrees: ONE packed u64 atomic per edge per side ----------------
// bits [39:0]  = sum of w * 2^24 (fixed point, exact integer adds)
// bits [63:40] = count
__global__ void deg_pk_kernel(const float* __restrict__ ew, const int* __restrict__ src,
                              const int* __restrict__ dst,
                              unsigned long long* __restrict__ out_pk,
                              unsigned long long* __restrict__ in_pk, int E) {
    int stride = gridDim.x * blockDim.x;
    for (int e = blockIdx.x * blockDim.x + threadIdx.x; e < E; e += stride) {
        float w = ew[e];
        unsigned long long v = (1ULL << 40) |
            (unsigned long long)__float2uint_rn(w * 16777216.0f);
        atomicAdd(&out_pk[src[e]], v);
        atomicAdd(&in_pk[dst[e]], v);
    }
}

__global__ void unpack_deg(const unsigned long long* __restrict__ out_pk,
                           const unsigned long long* __restrict__ in_pk,
                           float* __restrict__ out_wsum, float* __restrict__ in_wsum,
                           int* __restrict__ out_cnt, int* __restrict__ in_cnt, int n) {
    int i = blockIdx.x * blockDim.x + threadIdx.x;
    if (i >= n) return;
    const unsigned long long M40 = (1ULL << 40) - 1;
    unsigned long long o = out_pk[i], p = in_pk[i];
    out_cnt[i] = (int)(o >> 40);
    in_cnt[i]  = (int)(p >> 40);
    out_wsum[i] = (float)(o & M40) * (1.0f / 16777216.0f);
    in_wsum[i]  = (float)(p & M40) * (1.0f / 16777216.0f);
}

// ---------------- exclusive scan of in-degree counts (single block) ----------------
__global__ void scan_kernel(const int* __restrict__ cnt, int* __restrict__ row_start,
                            int* __restrict__ cursor, int n) {
    __shared__ int ls[1024];
    int tid = threadIdx.x;
    int chunk = (n + 1023) >> 10;
    int begin = tid * chunk;
    int end = begin + chunk; if (end > n) end = n;
    int s = 0;
    for (int i = begin; i < end; ++i) s += cnt[i];
    ls[tid] = s;
    __syncthreads();
    for (int d = 1; d < 1024; d <<= 1) {
        int v = (tid >= d) ? ls[tid - d] : 0;
        __syncthreads();
        ls[tid] += v;
        __syncthreads();
    }
    int run = ls[tid] - s;
    for (int i = begin; i < end; ++i) {
        row_start[i] = run;
        cursor[i] = run;
        run += cnt[i];
    }
}

// ---------------- bucket edge ids by dst ----------------
__global__ void scatter_kernel(const int* __restrict__ dst, int* __restrict__ cursor,
                               int* __restrict__ sorted_eid, int E) {
    int stride = gridDim.x * blockDim.x;
    for (int e = blockIdx.x * blockDim.x + threadIdx.x; e < E; e += stride) {
        int p = atomicAdd(&cursor[dst[e]], 1);
        sorted_eid[p] = e;
    }
}

// ---------------- pack fp32 matrix -> hi/lo bf16 u32 (row-major) ----------------
__global__ void pack_rows(const float4* __restrict__ X, u32x4* __restrict__ P, int n4) {
    int stride = gridDim.x * blockDim.x;
    for (int i = blockIdx.x * blockDim.x + threadIdx.x; i < n4; i += stride) {
        float4 x = X[i];
        u32x4 o;
        o.x = pack_hl(x.x); o.y = pack_hl(x.y);
        o.z = pack_hl(x.z); o.w = pack_hl(x.w);
        P[i] = o;
    }
}

// ---------------- pack + transpose weight: W[K][Nn] -> Bt[Nn][K] ----------------
__global__ void pack_wt(const float* __restrict__ W, uint32_t* __restrict__ Bt,
                        int K, int Nn) {
    int total = K * Nn;
    int stride = gridDim.x * blockDim.x;
    for (int idx = blockIdx.x * blockDim.x + threadIdx.x; idx < total; idx += stride) {
        int k = idx / Nn, n = idx - k * Nn;
        Bt[(size_t)n * K + k] = pack_hl(W[idx]);
    }
}

// ---------------- split-bf16 MFMA GEMM ----------------
// C[M,Nout] = A[M,K] @ B[K,Nout], A packed (main|res), Bt packed [Nout][K].
// 128x128 tile, BK=32, 4 waves (2x2), each wave 64x64 via 4x4 16x16x32 fragments.
// D = Am@Bm + Am@Br + Ar@Bm  (fp32-class accuracy).
__device__ inline void split_frag(const u32x4& lo, const u32x4& hi,
                                  short8& mainf, short8& resf) {
    u32x4 mm, rr;
    mm.x = __builtin_amdgcn_perm(lo.y, lo.x, 0x05040100u);
    mm.y = __builtin_amdgcn_perm(lo.w, lo.z, 0x05040100u);
    mm.z = __builtin_amdgcn_perm(hi.y, hi.x, 0x05040100u);
    mm.w = __builtin_amdgcn_perm(hi.w, hi.z, 0x05040100u);
    rr.x = __builtin_amdgcn_perm(lo.y, lo.x, 0x07060302u);
    rr.y = __builtin_amdgcn_perm(lo.w, lo.z, 0x07060302u);
    rr.z = __builtin_amdgcn_perm(hi.y, hi.x, 0x07060302u);
    rr.w = __builtin_amdgcn_perm(hi.w, hi.z, 0x07060302u);
    mainf = __builtin_bit_cast(short8, mm);
    resf  = __builtin_bit_cast(short8, rr);
}

template <bool OUT_BF16, bool ROWSCALE>
__global__ __launch_bounds__(256, 1) void gemm_split(
        const uint32_t* __restrict__ Apk, const uint32_t* __restrict__ Btpk,
        void* __restrict__ Cout, const int* __restrict__ rowcnt,
        int M, int Nout, int K) {
    __shared__ uint32_t Al[128 * 32];
    __shared__ uint32_t Bl[128 * 32];
    const int tid = threadIdx.x;
    const int lane = tid & 63, wid = tid >> 6;
    const int wm = wid >> 1, wn = wid & 1;
    const int l15 = lane & 15, lhi = lane >> 4;
    const int brow = blockIdx.x * 128, bcol = blockIdx.y * 128;

    f32x4 acc[4][4];
#pragma unroll
    for (int m = 0; m < 4; ++m)
#pragma unroll
        for (int n = 0; n < 4; ++n) acc[m][n] = f32x4{0.f, 0.f, 0.f, 0.f};

    for (int k0 = 0; k0 < K; k0 += 32) {
        // stage: each 16B chunk (r, c16) of the tile goes to LINEAR lds slot,
        // global source column pre-swizzled: c16s = c16 ^ (r&7)
#pragma unroll
        for (int i = 0; i < 4; ++i) {
            int chunk = i * 256 + tid;
            int r = chunk >> 3, c16 = chunk & 7;
            int c16s = c16 ^ (r & 7);
            gld_lds16(Apk + (size_t)(brow + r) * K + k0 + c16s * 4, Al + chunk * 4);
            gld_lds16(Btpk + (size_t)(bcol + r) * K + k0 + c16s * 4, Bl + chunk * 4);
        }
        __syncthreads();

        u32x4 apk[4][2], bpk[4][2];
#pragma unroll
        for (int m = 0; m < 4; ++m) {
            int row = wm * 64 + m * 16 + l15;
            const uint32_t* base = Al + row * 32;
            int rs = row & 7;
            apk[m][0] = *(const u32x4*)(base + (((lhi << 1) ^ rs) << 2));
            apk[m][1] = *(const u32x4*)(base + ((((lhi << 1) | 1) ^ rs) << 2));
        }
#pragma unroll
        for (int n = 0; n < 4; ++n) {
            int col = wn * 64 + n * 16 + l15;
            const uint32_t* base = Bl + col * 32;
            int rs = col & 7;
            bpk[n][0] = *(const u32x4*)(base + (((lhi << 1) ^ rs) << 2));
            bpk[n][1] = *(const u32x4*)(base + ((((lhi << 1) | 1) ^ rs) << 2));
        }
        short8 am[4], ar[4], bm[4], br[4];
#pragma unroll
        for (int m = 0; m < 4; ++m) split_frag(apk[m][0], apk[m][1], am[m], ar[m]);
#pragma unroll
        for (int n = 0; n < 4; ++n) split_frag(bpk[n][0], bpk[n][1], bm[n], br[n]);

#pragma unroll
        for (int m = 0; m < 4; ++m)
#pragma unroll
            for (int n = 0; n < 4; ++n) {
                f32x4 c = acc[m][n];
                c = __builtin_amdgcn_mfma_f32_16x16x32_bf16(ar[m], bm[n], c, 0, 0, 0);
                c = __builtin_amdgcn_mfma_f32_16x16x32_bf16(am[m], br[n], c, 0, 0, 0);
                c = __builtin_amdgcn_mfma_f32_16x16x32_bf16(am[m], bm[n], c, 0, 0, 0);
                acc[m][n] = c;
            }
        __syncthreads();
    }

    // epilogue: C/D layout col = lane&15, row = (lane>>4)*4 + j   [m89-verified]
#pragma unroll
    for (int m = 0; m < 4; ++m) {
        int rbase = brow + wm * 64 + m * 16 + lhi * 4;
        float scl[4];
#pragma unroll
        for (int j = 0; j < 4; ++j) {
            scl[j] = 1.f;
            if (ROWSCALE && rbase + j < M)
                scl[j] = rsqrtf(fmaxf((float)rowcnt[rbase + j], 1.f));
        }
#pragma unroll
        for (int n = 0; n < 4; ++n) {
            int col = bcol + wn * 64 + n * 16 + l15;
#pragma unroll
            for (int j = 0; j < 4; ++j) {
                int row = rbase + j;
                if (row < M) {
                    float v = acc[m][n][j] * scl[j];
                    if (OUT_BF16)
                        ((__hip_bfloat16*)Cout)[(size_t)row * Nout + col] = __float2bfloat16(v);
                    else
                        ((float*)Cout)[(size_t)row * Nout + col] = v;
                }
            }
        }
    }
}

// ---------------- SpMM1: h1pk[d] = pack(relu(sum_e nw_e * h[src_e] + b1)) ----------------
__global__ void spmm1_kernel(const float* __restrict__ h, const float* __restrict__ ew,
                             const int* __restrict__ src,
                             const float* __restrict__ out_wsum, const float* __restrict__ in_wsum,
                             const int* __restrict__ row_start, const int* __restrict__ in_cnt,
                             const int* __restrict__ sorted_eid, const float* __restrict__ b1,
                             uint32_t* __restrict__ h1pk) {
    int node = blockIdx.x;
    int lane = threadIdx.x;  // 64 lanes * 4 = 256 feats
    int start = row_start[node], cnt = in_cnt[node];
    float rin = (cnt > 0) ? rsqrtf(in_wsum[node]) : 0.f;
    float4 acc = make_float4(0.f, 0.f, 0.f, 0.f);
    for (int j = 0; j < cnt; ++j) {
        int e = sorted_eid[start + j];
        int s = src[e];
        float w = ew[e] * rsqrtf(out_wsum[s]) * rin;
        float4 v = *(const float4*)&h[(size_t)s * H1_F + lane * 4];
        acc.x = fmaf(w, v.x, acc.x); acc.y = fmaf(w, v.y, acc.y);
        acc.z = fmaf(w, v.z, acc.z); acc.w = fmaf(w, v.w, acc.w);
    }
    float4 bb = *(const float4*)&b1[lane * 4];
    u32x4 o;
    o.x = pack_hl(fmaxf(acc.x + bb.x, 0.f));
    o.y = pack_hl(fmaxf(acc.y + bb.y, 0.f));
    o.z = pack_hl(fmaxf(acc.z + bb.z, 0.f));
    o.w = pack_hl(fmaxf(acc.w + bb.w, 0.f));
    *(u32x4*)&h1pk[(size_t)node * H1_F + lane * 4] = o;
}

// ---------------- SpMM2 (bf16 gather): out[d] = rsqrt(max(indeg,1))*sum h2[src] + b2 ----------------
__global__ void spmm2_kernel(const uint32_t* __restrict__ h2, const int* __restrict__ src,
                             const int* __restrict__ row_start, const int* __restrict__ in_cnt,
                             const int* __restrict__ sorted_eid, const float* __restrict__ b2,
                             float* __restrict__ out) {
    int node = blockIdx.x;
    int lane = threadIdx.x;  // 64 lanes * 2 bf16 = 128 feats
    int start = row_start[node], cnt = in_cnt[node];
    float2 acc = make_float2(0.f, 0.f);
    for (int j = 0; j < cnt; ++j) {
        int e = sorted_eid[start + j];
        int s = src[e];
        uint32_t v = h2[(size_t)s * (H2_F / 2) + lane];
        acc.x += __builtin_bit_cast(float, v << 16);
        acc.y += __builtin_bit_cast(float, v & 0xffff0000u);
    }
    float rin = rsqrtf(fmaxf((float)cnt, 1.f));
    float2 bb = *(const float2*)&b2[lane * 2];
    float2 r = make_float2(acc.x * rin + bb.x, acc.y * rin + bb.y);
    *(float2*)&out[(size_t)node * H2_F + lane * 2] = r;
}

extern "C" void kernel_launch(void* const* d_in, const int* in_sizes, int n_in,
                              void* d_out, int out_size, void* d_ws, size_t ws_size,
                              hipStream_t stream) {
    const float* features = (const float*)d_in[0];
    const float* edge_w   = (const float*)d_in[1];
    const int*   src      = (const int*)d_in[2];
    const int*   dst      = (const int*)d_in[3];
    const float* W1       = (const float*)d_in[4];
    const float* b1       = (const float*)d_in[5];
    const float* W2       = (const float*)d_in[6];
    const float* b2       = (const float*)d_in[7];
    float* out = (float*)d_out;

    const int N = in_sizes[0] / IN_F;   // 20000
    const int E = in_sizes[1];          // 640000

    char* base = (char*)d_ws;
    size_t off = 0;
    auto alloc = [&](size_t bytes) {
        char* p = base + off;
        off = (off + bytes + 255) & ~(size_t)255;
        return p;
    };
    unsigned long long* out_pk = (unsigned long long*)alloc((size_t)N * 8);
    unsigned long long* in_pk  = (unsigned long long*)alloc((size_t)N * 8);
    float* out_wsum   = (float*)alloc((size_t)N * 4);
    float* in_wsum    = (float*)alloc((size_t)N * 4);
    int*   out_cnt    = (int*)  alloc((size_t)N * 4);
    int*   in_cnt     = (int*)  alloc((size_t)N * 4);
    int*   row_start  = (int*)  alloc((size_t)N * 4);
    int*   cursor     = (int*)  alloc((size_t)N * 4);
    int*   sorted_eid = (int*)  alloc((size_t)E * 4);
    uint32_t* Bt1     = (uint32_t*)alloc((size_t)H1_F * IN_F * 4);
    uint32_t* Bt2     = (uint32_t*)alloc((size_t)H2_F * H1_F * 4);
    float* h_tmp1     = (float*)alloc((size_t)N * H1_F * 4);
    uint32_t* Apk     = (uint32_t*)alloc((size_t)MPAD * IN_F * 4);
    // overlays inside Apk region (sequential stream ordering makes this safe):
    uint32_t* h1pk = Apk;                              // [MPAD][256] u32 (rows<N written)
    uint32_t* h2b  = Apk + (size_t)MPAD * H1_F;        // [N][64] u32 of bf16x2
    (void)ws_size;

    hipMemsetAsync(out_pk, 0, (size_t)N * 8, stream);
    hipMemsetAsync(in_pk,  0, (size_t)N * 8, stream);

    deg_pk_kernel<<<1024, 256, 0, stream>>>(edge_w, src, dst, out_pk, in_pk, E);
    unpack_deg<<<(N + 255) / 256, 256, 0, stream>>>(out_pk, in_pk, out_wsum, in_wsum,
                                                    out_cnt, in_cnt, N);
    scan_kernel<<<1, 1024, 0, stream>>>(in_cnt, row_start, cursor, N);
    scatter_kernel<<<1024, 256, 0, stream>>>(dst, cursor, sorted_eid, E);

    // pack operands
    pack_rows<<<2048, 256, 0, stream>>>((const float4*)features, (u32x4*)Apk,
                                        N * IN_F / 4);
    pack_wt<<<512, 256, 0, stream>>>(W1, Bt1, IN_F, H1_F);
    pack_wt<<<128, 256, 0, stream>>>(W2, Bt2, H1_F, H2_F);

    // layer 1
    dim3 g1((MPAD) / 128, H1_F / 128);
    gemm_split<false, false><<<g1, 256, 0, stream>>>(Apk, Bt1, h_tmp1, nullptr,
                                                     N, H1_F, IN_F);
    spmm1_kernel<<<N, 64, 0, stream>>>(h_tmp1, edge_w, src, out_wsum, in_wsum,
                                       row_start, in_cnt, sorted_eid, b1, h1pk);
    // layer 2
    dim3 g2((MPAD) / 128, H2_F / 128);
    gemm_split<true, true><<<g2, 256, 0, stream>>>(h1pk, Bt2, h2b, out_cnt,
                                                   N, H2_F, H1_F);
    spmm2_kernel<<<N, 64, 0, stream>>>(h2b, src, row_start, in_cnt, sorted_eid, b2, out);
}

// Round 3
// 318.489 us; speedup vs baseline: 1.5057x; 1.1703x over previous
//
#include <hip/hip_runtime.h>
#include <hip/hip_bf16.h>
#include <stdint.h>

#define IN_F 512
#define H1_F 256
#define H2_F 128
#define MPAD 20096   // 157*128, padded row count for 128-row GEMM tiles

typedef __attribute__((ext_vector_type(8))) short short8;   // 8 bf16 (4 VGPRs)
typedef __attribute__((ext_vector_type(4))) float f32x4;
typedef __attribute__((ext_vector_type(4))) uint32_t u32x4;

// ---- fp32 -> (bf16 main | bf16 residual) packed in one u32 ----
__device__ inline uint32_t pack_hl(float x) {
    __hip_bfloat16 m = __float2bfloat16(x);
    float mf = __bfloat162float(m);
    __hip_bfloat16 r = __float2bfloat16(x - mf);
    return (uint32_t)__builtin_bit_cast(unsigned short, m) |
           ((uint32_t)__builtin_bit_cast(unsigned short, r) << 16);
}

__device__ inline float bf_lo(uint32_t v) { return __builtin_bit_cast(float, v << 16); }
__device__ inline float bf_hi(uint32_t v) { return __builtin_bit_cast(float, v & 0xffff0000u); }

__device__ inline void gld_lds16(const uint32_t* g, uint32_t* l) {
    __builtin_amdgcn_global_load_lds((const __attribute__((address_space(1))) uint32_t*)g,
                                     (__attribute__((address_space(3))) uint32_t*)l,
                                     16, 0, 0);
}

// ---------------- pass 1: out-side packed atomic + in-side count/slot ----------------
// out_pk bits [39:0] = sum w*2^24 fixed point; bits [63:40] = count
__global__ void count_kernel(const float* __restrict__ ew, const int* __restrict__ src,
                             const int* __restrict__ dst,
                             unsigned long long* __restrict__ out_pk,
                             int* __restrict__ in_cnt, int* __restrict__ slot, int E) {
    int stride = gridDim.x * blockDim.x;
    for (int e = blockIdx.x * blockDim.x + threadIdx.x; e < E; e += stride) {
        float w = ew[e];
        unsigned long long v = (1ULL << 40) |
            (unsigned long long)__float2uint_rn(w * 16777216.0f);
        atomicAdd(&out_pk[src[e]], v);
        slot[e] = atomicAdd(&in_cnt[dst[e]], 1);
    }
}

__global__ void unpack_out(const unsigned long long* __restrict__ out_pk,
                           int* __restrict__ out_cnt, float* __restrict__ out_rs, int n) {
    int i = blockIdx.x * blockDim.x + threadIdx.x;
    if (i >= n) return;
    unsigned long long o = out_pk[i];
    int c = (int)(o >> 40);
    out_cnt[i] = c;
    float ws = (float)(o & ((1ULL << 40) - 1)) * (1.0f / 16777216.0f);
    out_rs[i] = (c > 0) ? rsqrtf(ws) : 0.f;
}

// ---------------- exclusive scan of in-degree counts (single block) ----------------
__global__ void scan_kernel(const int* __restrict__ cnt, int* __restrict__ row_start, int n) {
    __shared__ int ls[1024];
    int tid = threadIdx.x;
    int chunk = (n + 1023) >> 10;
    int begin = tid * chunk;
    int end = begin + chunk; if (end > n) end = n;
    int s = 0;
    for (int i = begin; i < end; ++i) s += cnt[i];
    ls[tid] = s;
    __syncthreads();
    for (int d = 1; d < 1024; d <<= 1) {
        int v = (tid >= d) ? ls[tid - d] : 0;
        __syncthreads();
        ls[tid] += v;
        __syncthreads();
    }
    int run = ls[tid] - s;
    for (int i = begin; i < end; ++i) {
        row_start[i] = run;
        run += cnt[i];
    }
}

// ---------------- pass 2: atomic-free bucket write (src|ew packed u64) ----------------
__global__ void scatter2_kernel(const float* __restrict__ ew, const int* __restrict__ src,
                                const int* __restrict__ dst,
                                const int* __restrict__ row_start, const int* __restrict__ slot,
                                unsigned long long* __restrict__ s_meta, int E) {
    int stride = gridDim.x * blockDim.x;
    for (int e = blockIdx.x * blockDim.x + threadIdx.x; e < E; e += stride) {
        int p = row_start[dst[e]] + slot[e];
        unsigned long long m = (unsigned long long)(unsigned)src[e] |
            ((unsigned long long)__builtin_bit_cast(unsigned, ew[e]) << 32);
        s_meta[p] = m;
    }
}

// ---------------- per-node: in_wsum segment sum (no atomics) + nw precompute ----------------
__global__ void in_finalize(const unsigned long long* __restrict__ s_meta,
                            const float* __restrict__ out_rs,
                            const int* __restrict__ row_start, const int* __restrict__ in_cnt,
                            int* __restrict__ s_src, float* __restrict__ s_nw, int N) {
    int node = blockIdx.x;
    int lane = threadIdx.x;
    int start = row_start[node], cnt = in_cnt[node];
    float sum = 0.f;
    for (int j = lane; j < cnt; j += 64)
        sum += __builtin_bit_cast(float, (unsigned)(s_meta[start + j] >> 32));
    for (int d = 1; d < 64; d <<= 1) sum += __shfl_xor(sum, d);
    float rin = (cnt > 0) ? rsqrtf(sum) : 0.f;
    for (int j = lane; j < cnt; j += 64) {
        unsigned long long m = s_meta[start + j];
        int s = (int)(unsigned)m;
        float w = __builtin_bit_cast(float, (unsigned)(m >> 32));
        s_src[start + j] = s;
        s_nw[start + j] = w * out_rs[s] * rin;
    }
}

// ---------------- pack fp32 matrix -> hi/lo bf16 u32 (row-major) ----------------
__global__ void pack_rows(const float4* __restrict__ X, u32x4* __restrict__ P, int n4) {
    int stride = gridDim.x * blockDim.x;
    for (int i = blockIdx.x * blockDim.x + threadIdx.x; i < n4; i += stride) {
        float4 x = X[i];
        u32x4 o;
        o.x = pack_hl(x.x); o.y = pack_hl(x.y);
        o.z = pack_hl(x.z); o.w = pack_hl(x.w);
        P[i] = o;
    }
}

// ---------------- pack + transpose weight: W[K][Nn] -> Bt[Nn][K] ----------------
__global__ void pack_wt(const float* __restrict__ W, uint32_t* __restrict__ Bt,
                        int K, int Nn) {
    int total = K * Nn;
    int stride = gridDim.x * blockDim.x;
    for (int idx = blockIdx.x * blockDim.x + threadIdx.x; idx < total; idx += stride) {
        int k = idx / Nn, n = idx - k * Nn;
        Bt[(size_t)n * K + k] = pack_hl(W[idx]);
    }
}

// ---------------- split-bf16 MFMA GEMM (128x128 tile, BK=32, 4 waves) ----------------
// D = Am@Bm + Am@Br + Ar@Bm  (fp32-class accuracy). Always writes bf16.
__device__ inline void split_frag(const u32x4& lo, const u32x4& hi,
                                  short8& mainf, short8& resf) {
    u32x4 mm, rr;
    mm.x = __builtin_amdgcn_perm(lo.y, lo.x, 0x05040100u);
    mm.y = __builtin_amdgcn_perm(lo.w, lo.z, 0x05040100u);
    mm.z = __builtin_amdgcn_perm(hi.y, hi.x, 0x05040100u);
    mm.w = __builtin_amdgcn_perm(hi.w, hi.z, 0x05040100u);
    rr.x = __builtin_amdgcn_perm(lo.y, lo.x, 0x07060302u);
    rr.y = __builtin_amdgcn_perm(lo.w, lo.z, 0x07060302u);
    rr.z = __builtin_amdgcn_perm(hi.y, hi.x, 0x07060302u);
    rr.w = __builtin_amdgcn_perm(hi.w, hi.z, 0x07060302u);
    mainf = __builtin_bit_cast(short8, mm);
    resf  = __builtin_bit_cast(short8, rr);
}

template <bool ROWSCALE>
__global__ __launch_bounds__(256, 1) void gemm_split(
        const uint32_t* __restrict__ Apk, const uint32_t* __restrict__ Btpk,
        __hip_bfloat16* __restrict__ Cout, const int* __restrict__ rowcnt,
        int M, int Nout, int K) {
    __shared__ uint32_t Al[128 * 32];
    __shared__ uint32_t Bl[128 * 32];
    const int tid = threadIdx.x;
    const int lane = tid & 63, wid = tid >> 6;
    const int wm = wid >> 1, wn = wid & 1;
    const int l15 = lane & 15, lhi = lane >> 4;
    const int brow = blockIdx.x * 128, bcol = blockIdx.y * 128;

    f32x4 acc[4][4];
#pragma unroll
    for (int m = 0; m < 4; ++m)
#pragma unroll
        for (int n = 0; n < 4; ++n) acc[m][n] = f32x4{0.f, 0.f, 0.f, 0.f};

    for (int k0 = 0; k0 < K; k0 += 32) {
#pragma unroll
        for (int i = 0; i < 4; ++i) {
            int chunk = i * 256 + tid;
            int r = chunk >> 3, c16 = chunk & 7;
            int c16s = c16 ^ (r & 7);
            gld_lds16(Apk + (size_t)(brow + r) * K + k0 + c16s * 4, Al + chunk * 4);
            gld_lds16(Btpk + (size_t)(bcol + r) * K + k0 + c16s * 4, Bl + chunk * 4);
        }
        __syncthreads();

        u32x4 apk[4][2], bpk[4][2];
#pragma unroll
        for (int m = 0; m < 4; ++m) {
            int row = wm * 64 + m * 16 + l15;
            const uint32_t* base = Al + row * 32;
            int rs = row & 7;
            apk[m][0] = *(const u32x4*)(base + (((lhi << 1) ^ rs) << 2));
            apk[m][1] = *(const u32x4*)(base + ((((lhi << 1) | 1) ^ rs) << 2));
        }
#pragma unroll
        for (int n = 0; n < 4; ++n) {
            int col = wn * 64 + n * 16 + l15;
            const uint32_t* base = Bl + col * 32;
            int rs = col & 7;
            bpk[n][0] = *(const u32x4*)(base + (((lhi << 1) ^ rs) << 2));
            bpk[n][1] = *(const u32x4*)(base + ((((lhi << 1) | 1) ^ rs) << 2));
        }
        short8 am[4], ar[4], bm[4], br[4];
#pragma unroll
        for (int m = 0; m < 4; ++m) split_frag(apk[m][0], apk[m][1], am[m], ar[m]);
#pragma unroll
        for (int n = 0; n < 4; ++n) split_frag(bpk[n][0], bpk[n][1], bm[n], br[n]);

#pragma unroll
        for (int m = 0; m < 4; ++m)
#pragma unroll
            for (int n = 0; n < 4; ++n) {
                f32x4 c = acc[m][n];
                c = __builtin_amdgcn_mfma_f32_16x16x32_bf16(ar[m], bm[n], c, 0, 0, 0);
                c = __builtin_amdgcn_mfma_f32_16x16x32_bf16(am[m], br[n], c, 0, 0, 0);
                c = __builtin_amdgcn_mfma_f32_16x16x32_bf16(am[m], bm[n], c, 0, 0, 0);
                acc[m][n] = c;
            }
        __syncthreads();
    }

    // epilogue: C/D layout col = lane&15, row = (lane>>4)*4 + j
#pragma unroll
    for (int m = 0; m < 4; ++m) {
        int rbase = brow + wm * 64 + m * 16 + lhi * 4;
        float scl[4];
#pragma unroll
        for (int j = 0; j < 4; ++j) {
            scl[j] = 1.f;
            if (ROWSCALE && rbase + j < M)
                scl[j] = rsqrtf(fmaxf((float)rowcnt[rbase + j], 1.f));
        }
#pragma unroll
        for (int n = 0; n < 4; ++n) {
            int col = bcol + wn * 64 + n * 16 + l15;
#pragma unroll
            for (int j = 0; j < 4; ++j) {
                int row = rbase + j;
                if (row < M)
                    Cout[(size_t)row * Nout + col] = __float2bfloat16(acc[m][n][j] * scl[j]);
            }
        }
    }
}

// ---------------- SpMM1, XCD-affine 4-slice (64 feats/slice), bf16 gather ----------------
// grid = 4 * ceil(N/4); slice = bx & 3 (XCD-correlated); 4 waves = 4 nodes/block.
__global__ void spmm1_sliced(const uint32_t* __restrict__ h32,  // [*, 128] u32 of bf16x2
                             const int* __restrict__ s_src, const float* __restrict__ s_nw,
                             const int* __restrict__ row_start, const int* __restrict__ in_cnt,
                             const float* __restrict__ b1, uint32_t* __restrict__ h1pk, int N) {
    int bx = blockIdx.x;
    int slice = bx & 3;
    int grp = bx >> 2;
    int wid = threadIdx.x >> 6, lane = threadIdx.x & 63;
    int node = grp * 4 + wid;
    if (node >= N) return;
    int start = row_start[node], cnt = in_cnt[node];
    int es = lane >> 5, fl = lane & 31;
    const uint32_t* hbase = h32 + slice * 32 + fl;
    float ax = 0.f, ay = 0.f;
    for (int j = es; j < cnt; j += 2) {
        int p = start + j;
        int s = s_src[p];
        float w = s_nw[p];
        uint32_t v = hbase[(size_t)s * 128];
        ax = fmaf(w, bf_lo(v), ax);
        ay = fmaf(w, bf_hi(v), ay);
    }
    ax += __shfl_xor(ax, 32);
    ay += __shfl_xor(ay, 32);
    if (es == 0) {
        int fi = slice * 64 + fl * 2;
        float2 bb = *(const float2*)&b1[fi];
        uint2 o;
        o.x = pack_hl(fmaxf(ax + bb.x, 0.f));
        o.y = pack_hl(fmaxf(ay + bb.y, 0.f));
        *(uint2*)&h1pk[(size_t)node * H1_F + fi] = o;
    }
}

// ---------------- SpMM2, XCD-affine 2-slice (64 feats/slice), bf16 gather ----------------
__global__ void spmm2_sliced(const uint32_t* __restrict__ h2_32,  // [*, 64] u32 of bf16x2
                             const int* __restrict__ s_src,
                             const int* __restrict__ row_start, const int* __restrict__ in_cnt,
                             const float* __restrict__ b2, float* __restrict__ out, int N) {
    int bx = blockIdx.x;
    int slice = bx & 1;
    int grp = bx >> 1;
    int wid = threadIdx.x >> 6, lane = threadIdx.x & 63;
    int node = grp * 4 + wid;
    if (node >= N) return;
    int start = row_start[node], cnt = in_cnt[node];
    int es = lane >> 5, fl = lane & 31;
    const uint32_t* hbase = h2_32 + slice * 32 + fl;
    float ax = 0.f, ay = 0.f;
    for (int j = es; j < cnt; j += 2) {
        int p = start + j;
        int s = s_src[p];
        uint32_t v = hbase[(size_t)s * 64];
        ax += bf_lo(v);
        ay += bf_hi(v);
    }
    ax += __shfl_xor(ax, 32);
    ay += __shfl_xor(ay, 32);
    if (es == 0) {
        float rin = rsqrtf(fmaxf((float)cnt, 1.f));
        int fi = slice * 64 + fl * 2;
        float2 bb = *(const float2*)&b2[fi];
        float2 r = make_float2(ax * rin + bb.x, ay * rin + bb.y);
        *(float2*)&out[(size_t)node * H2_F + fi] = r;
    }
}

extern "C" void kernel_launch(void* const* d_in, const int* in_sizes, int n_in,
                              void* d_out, int out_size, void* d_ws, size_t ws_size,
                              hipStream_t stream) {
    const float* features = (const float*)d_in[0];
    const float* edge_w   = (const float*)d_in[1];
    const int*   src      = (const int*)d_in[2];
    const int*   dst      = (const int*)d_in[3];
    const float* W1       = (const float*)d_in[4];
    const float* b1       = (const float*)d_in[5];
    const float* W2       = (const float*)d_in[6];
    const float* b2       = (const float*)d_in[7];
    float* out = (float*)d_out;

    const int N = in_sizes[0] / IN_F;   // 20000
    const int E = in_sizes[1];          // 640000

    char* base = (char*)d_ws;
    size_t off = 0;
    auto alloc = [&](size_t bytes) {
        char* p = base + off;
        off = (off + bytes + 255) & ~(size_t)255;
        return p;
    };
    unsigned long long* out_pk = (unsigned long long*)alloc((size_t)N * 8);
    int*   out_cnt   = (int*)  alloc((size_t)N * 4);
    float* out_rs    = (float*)alloc((size_t)N * 4);
    int*   in_cnt    = (int*)  alloc((size_t)N * 4);
    int*   row_start = (int*)  alloc((size_t)N * 4);
    int*   slot      = (int*)  alloc((size_t)E * 4);
    unsigned long long* s_meta = (unsigned long long*)alloc((size_t)E * 8);
    int*   s_src     = (int*)  alloc((size_t)E * 4);
    float* s_nw      = (float*)alloc((size_t)E * 4);
    uint32_t* Bt1    = (uint32_t*)alloc((size_t)H1_F * IN_F * 4);
    uint32_t* Bt2    = (uint32_t*)alloc((size_t)H2_F * H1_F * 4);
    __hip_bfloat16* h_bf = (__hip_bfloat16*)alloc((size_t)MPAD * H1_F * 2);
    uint32_t* Apk    = (uint32_t*)alloc((size_t)MPAD * IN_F * 4);
    // overlays inside Apk (Apk dead after GEMM1; sequential stream makes this safe)
    uint32_t* h1pk = Apk;                               // [MPAD][256] u32
    uint32_t* h2b  = Apk + (size_t)MPAD * H1_F;         // [N][64] u32 of bf16x2
    (void)ws_size;

    hipMemsetAsync(out_pk, 0, (size_t)N * 8, stream);
    hipMemsetAsync(in_cnt, 0, (size_t)N * 4, stream);

    // ---- CSR build + norms ----
    count_kernel<<<1024, 256, 0, stream>>>(edge_w, src, dst, out_pk, in_cnt, slot, E);
    unpack_out<<<(N + 255) / 256, 256, 0, stream>>>(out_pk, out_cnt, out_rs, N);
    scan_kernel<<<1, 1024, 0, stream>>>(in_cnt, row_start, N);
    scatter2_kernel<<<1024, 256, 0, stream>>>(edge_w, src, dst, row_start, slot, s_meta, E);
    in_finalize<<<N, 64, 0, stream>>>(s_meta, out_rs, row_start, in_cnt, s_src, s_nw, N);

    // ---- operand packing ----
    pack_rows<<<2048, 256, 0, stream>>>((const float4*)features, (u32x4*)Apk, N * IN_F / 4);
    pack_wt<<<512, 256, 0, stream>>>(W1, Bt1, IN_F, H1_F);
    pack_wt<<<128, 256, 0, stream>>>(W2, Bt2, H1_F, H2_F);

    // ---- layer 1 ----
    dim3 g1(MPAD / 128, H1_F / 128);
    gemm_split<false><<<g1, 256, 0, stream>>>(Apk, Bt1, h_bf, nullptr, N, H1_F, IN_F);
    int grp = (N + 3) / 4;
    spmm1_sliced<<<grp * 4, 256, 0, stream>>>((const uint32_t*)h_bf, s_src, s_nw,
                                              row_start, in_cnt, b1, h1pk, N);
    // ---- layer 2 ----
    dim3 g2(MPAD / 128, H2_F / 128);
    gemm_split<true><<<g2, 256, 0, stream>>>(h1pk, Bt2, (__hip_bfloat16*)h2b, out_cnt,
                                             N, H2_F, H1_F);
    spmm2_sliced<<<grp * 2, 256, 0, stream>>>(h2b, s_src, row_start, in_cnt, b2, out, N);
}